// Round 7
// baseline (1604.497 us; speedup 1.0000x reference)
//
#include <hip/hip_runtime.h>

#define NN 100000
#define NE 1600000
#define INC 128
#define TE 32
#define OC 128
#define NR 8
#define NBASES 8
#define FT 160
#define KP 168          // padded K stride (bf16) for LDS feat tile
#define KW 160          // unpadded K stride for global Wt
#define TN 32           // nodes per mega block
#define AGS 164         // agg row stride in f32 (padded: 164%32=4 -> bank spread)
#define NBKT 3125       // NN/32 dst buckets (exact)
#define NCH 256         // edge chunks
#define EPB 6250        // edges per chunk (256*6250 = NE exactly)
#define CAP 768         // per-bucket edge cap (mean 512, +11 sigma)

typedef float f32x4 __attribute__((ext_vector_type(4)));
typedef __bf16 bf16x8 __attribute__((ext_vector_type(8)));

__device__ __forceinline__ unsigned f2bf1(float f) {
    unsigned u = __float_as_uint(f);
    return (u + 0x7fffu + ((u >> 16) & 1u)) >> 16;   // RNE to bf16
}

// exclusive block scan over 256 per-thread values (Hillis-Steele in LDS)
__device__ __forceinline__ int bscan_excl(int v, int* tmp) {
    int tid = threadIdx.x;
    tmp[tid] = v; __syncthreads();
#pragma unroll
    for (int d = 1; d < 256; d <<= 1) {
        int t = (tid >= d) ? tmp[tid - d] : 0;
        __syncthreads();
        tmp[tid] += t;
        __syncthreads();
    }
    return tmp[tid] - v;
}

// ---- merged: chunk histograms (blocks 0..NCH-1) + Wt/h precompute (rest) ----
__global__ __launch_bounds__(256) void k_prep(
    const float* __restrict__ x, const int* __restrict__ nt,
    const float* __restrict__ emb, const float* __restrict__ comp,
    const float* __restrict__ bases, const float* __restrict__ rootw,
    const int* __restrict__ ei,
    unsigned short* __restrict__ h, unsigned short* __restrict__ Wt,
    int* __restrict__ ghist) {
    __shared__ int hist[NBKT];
    int tid = threadIdx.x;
    int b = blockIdx.x;
    if (b < NCH) {
        for (int j = tid; j < NBKT; j += 256) hist[j] = 0;
        __syncthreads();
        int e0 = b * EPB;
#pragma unroll
        for (int k = 0; k < 25; k++) {
            int i = k * 256 + tid;
            if (i < EPB) atomicAdd(&hist[ei[NE + e0 + i] >> 5], 1);
        }
        __syncthreads();
        int* g = ghist + (size_t)b * NBKT;
        for (int j = tid; j < NBKT; j += 256) g[j] = hist[j];
        return;
    }
    int idx = (b - NCH) * 256 + tid;
    if (idx < 9 * 128 * KW) {
        int ridx = idx / (128 * KW);
        int rem  = idx % (128 * KW);
        int o = rem / KW;
        int k = rem % KW;
        float v;
        if (ridx < NR) {
            v = 0.f;
#pragma unroll
            for (int bb = 0; bb < NBASES; bb++)
                v += comp[ridx * NBASES + bb] * bases[(bb * FT + k) * OC + o];
        } else {
            v = rootw[k * OC + o];
        }
        Wt[idx] = (unsigned short)f2bf1(v);
    }
    if (idx < NN * 20) {
        int n = idx / 20, c = idx % 20;
        f32x4 v0, v1;
        if (c < 16) {
            const float* p = x + (size_t)n * INC + c * 8;
            v0 = *(const f32x4*)p; v1 = *(const f32x4*)(p + 4);
        } else {
            int tt = nt[n];
            const float* p = emb + tt * TE + (c - 16) * 8;
            v0 = *(const f32x4*)p; v1 = *(const f32x4*)(p + 4);
        }
        uint4 o;
        o.x = f2bf1(v0.x) | (f2bf1(v0.y) << 16);
        o.y = f2bf1(v0.z) | (f2bf1(v0.w) << 16);
        o.z = f2bf1(v1.x) | (f2bf1(v1.y) << 16);
        o.w = f2bf1(v1.z) | (f2bf1(v1.w) << 16);
        *(uint4*)(h + (size_t)n * FT + c * 8) = o;
    }
}

// thread-per-j, loop-over-b: coalesced column sums
__global__ void k_total(const int* __restrict__ ghist, int* __restrict__ total) {
    int j = blockIdx.x * 256 + threadIdx.x;
    if (j >= NBKT) return;
    int s = 0;
#pragma unroll 8
    for (int b = 0; b < NCH; b++) s += ghist[(size_t)b * NBKT + j];
    total[j] = s;
}

__global__ void k_scanTot(const int* __restrict__ total, int* __restrict__ bstart) {
    __shared__ int tmp[256];
    int tid = threadIdx.x, s = 0, i0 = tid * 13;
#pragma unroll
    for (int i = 0; i < 13; i++) { int j = i0 + i; if (j < NBKT) s += total[j]; }
    int run = bscan_excl(s, tmp);
#pragma unroll
    for (int i = 0; i < 13; i++) { int j = i0 + i; if (j < NBKT) { bstart[j] = run; run += total[j]; } }
    if (tid == 0) bstart[NBKT] = NE;
}

// thread-per-j serial prefix over b (coalesced): ghist[b][j] -> absolute chunk start
__global__ void k_offsets(int* __restrict__ ghist, const int* __restrict__ bstart) {
    int j = blockIdx.x * 256 + threadIdx.x;
    if (j >= NBKT) return;
    int run = bstart[j];
#pragma unroll 4
    for (int b = 0; b < NCH; b++) {
        int v = ghist[(size_t)b * NBKT + j];
        ghist[(size_t)b * NBKT + j] = run;
        run += v;
    }
}

// scatter packed entries (src | rel<<17 | dst_local<<20) into bucket-contiguous slots
__global__ __launch_bounds__(256) void k_scatter(const int* __restrict__ ei, const int* __restrict__ et,
                                                 const int* __restrict__ ghist, unsigned* __restrict__ slots) {
    __shared__ int cur[NBKT];
    int tid = threadIdx.x, b = blockIdx.x;
    for (int j = tid; j < NBKT; j += 256) cur[j] = ghist[(size_t)b * NBKT + j];
    __syncthreads();
    int e0 = b * EPB;
#pragma unroll
    for (int k = 0; k < 25; k++) {
        int i = k * 256 + tid;
        if (i < EPB) {
            int e = e0 + i;
            int s = ei[e], d = ei[NE + e], r = et[e];
            int pos = atomicAdd(&cur[d >> 5], 1);
            slots[pos] = (unsigned)s | ((unsigned)r << 17) | ((unsigned)(d & 31) << 20);
        }
    }
}

// ---- fused: rel-sort + root GEMM + per-relation (edge-parallel ds_add mean -> GEMM) + bias + ReLU ----
// LDS: agg 20992 + feat 10752 + sl 3072 + cnt256 1024 + small ~= 36 KB -> 4 blocks/CU
__global__ __launch_bounds__(256, 4) void k_mega(
    const unsigned short* __restrict__ h, const float* __restrict__ bias,
    const unsigned short* __restrict__ Wt, const int* __restrict__ bstart,
    const unsigned* __restrict__ slots, float* __restrict__ out) {
    __shared__ float agg[TN * AGS];           // f32 accumulators (phase1: sl_in scratch overlay)
    __shared__ unsigned short feat[TN * KP];  // bf16 MFMA A tile
    __shared__ unsigned sl[CAP];
    __shared__ int cnt256[256];               // per (rel, dst_local) edge counts
    __shared__ int tot8[8], pk8[9], cur8[8];

    const int tid = threadIdx.x;
    const int lane = tid & 63;
    const int wave = tid >> 6;
    const int j = blockIdx.x;
    const int n0 = j * TN;

    // ---- phase 1: stage + count + rel-only sort (8 keys) ----
    int s0 = bstart[j];
    int m = bstart[j + 1] - s0; if (m > CAP) m = CAP;
    unsigned* sl_in = reinterpret_cast<unsigned*>(agg);
    for (int i = tid; i < m; i += 256) sl_in[i] = slots[s0 + i];
    cnt256[tid] = 0;
    __syncthreads();
    for (int i = tid; i < m; i += 256) {
        unsigned v = sl_in[i];
        atomicAdd(&cnt256[((v >> 17) & 7u) * 32u + ((v >> 20) & 31u)], 1);
    }
    __syncthreads();
    if (tid < 8) {
        int s = 0;
#pragma unroll
        for (int q = 0; q < 32; q++) s += cnt256[tid * 32 + q];
        tot8[tid] = s;
    }
    __syncthreads();
    if (tid == 0) {
        int run = 0;
#pragma unroll
        for (int rr = 0; rr < 8; rr++) { pk8[rr] = run; run += tot8[rr]; }
        pk8[8] = run;
    }
    __syncthreads();
    if (tid < 8) cur8[tid] = pk8[tid];
    __syncthreads();
    for (int i = tid; i < m; i += 256) {
        unsigned v = sl_in[i];
        int p = atomicAdd(&cur8[(v >> 17) & 7u], 1);
        sl[p] = v & 0x01F1FFFFu;               // keep src (0..16) + dst_local (20..24)
    }
    __syncthreads();

    // ---- root feat tile from h; zero agg ----
    for (int i = tid; i < TN * 20; i += 256) {
        int nl = i / 20, c = i % 20;
        uint4 v = *reinterpret_cast<const uint4*>(h + (size_t)(n0 + nl) * FT + c * 8);
        *reinterpret_cast<uint4*>(&feat[nl * KP + c * 8]) = v;
    }
    for (int i = tid; i < TN * AGS / 4; i += 256)
        *reinterpret_cast<f32x4*>(agg + i * 4) = (f32x4){0.f, 0.f, 0.f, 0.f};

    f32x4 acc[4];   // acc[rt*2+ct], rt 0..1, ct 0..1
#pragma unroll
    for (int t = 0; t < 4; t++) acc[t] = (f32x4){0.f, 0.f, 0.f, 0.f};

    auto mfma_pass = [&](int ridx) {   // A from LDS feat, B straight from global (L2-resident)
        const unsigned short* fA = feat + (lane & 15) * KP + ((lane >> 4) * 8);
        const unsigned short* gB = Wt + (size_t)ridx * 128 * KW
                                   + (wave * 32 + (lane & 15)) * KW + ((lane >> 4) * 8);
#pragma unroll
        for (int kc = 0; kc < 5; kc++) {
            bf16x8 a0 = *reinterpret_cast<const bf16x8*>(fA + kc * 32);
            bf16x8 a1 = *reinterpret_cast<const bf16x8*>(fA + 16 * KP + kc * 32);
#pragma unroll
            for (int ct = 0; ct < 2; ct++) {
                bf16x8 b = *reinterpret_cast<const bf16x8*>(gB + ct * 16 * KW + kc * 32);
                acc[0 * 2 + ct] = __builtin_amdgcn_mfma_f32_16x16x32_bf16(a0, b, acc[0 * 2 + ct], 0, 0, 0);
                acc[1 * 2 + ct] = __builtin_amdgcn_mfma_f32_16x16x32_bf16(a1, b, acc[1 * 2 + ct], 0, 0, 0);
            }
        }
    };

    __syncthreads();

    // ---- per-rel: edge-parallel gather+ds_add, overlapped with prev MFMA ----
    const int g = tid >> 4, l = tid & 15;
    const unsigned* hw = reinterpret_cast<const unsigned*>(h);
    int prev = 8;   // root first
    for (int r = 0; r < NR; r++) {
        int rb = pk8[r], re = pk8[r + 1];
        for (int base = rb + g; base < re; base += 32) {   // 16 groups, batch-2
            int i1 = base + 16;
            unsigned v0 = sl[base];
            unsigned v1 = sl[(i1 < re) ? i1 : base];
            const unsigned* p0 = hw + (size_t)(v0 & 0x1FFFFu) * 80 + l;
            const unsigned* p1 = hw + (size_t)(v1 & 0x1FFFFu) * 80 + l;
            unsigned w0[5], w1[5];
#pragma unroll
            for (int c = 0; c < 5; c++) { w0[c] = p0[c * 16]; w1[c] = p1[c * 16]; }
            int d0 = (int)((v0 >> 20) & 31u);
            int d1 = (int)((v1 >> 20) & 31u);
            float* a0 = agg + d0 * AGS + 2 * l;
#pragma unroll
            for (int c = 0; c < 5; c++) {
                atomicAdd(a0 + 32 * c,     __uint_as_float(w0[c] << 16));
                atomicAdd(a0 + 32 * c + 1, __uint_as_float(w0[c] & 0xFFFF0000u));
            }
            if (i1 < re) {
                float* a1 = agg + d1 * AGS + 2 * l;
#pragma unroll
                for (int c = 0; c < 5; c++) {
                    atomicAdd(a1 + 32 * c,     __uint_as_float(w1[c] << 16));
                    atomicAdd(a1 + 32 * c + 1, __uint_as_float(w1[c] & 0xFFFF0000u));
                }
            }
        }
        mfma_pass(prev);
        __syncthreads();   // all ds_adds done; mfma done reading feat

        // convert agg -> feat bf16 (and re-zero agg; same thread owns both)
        {
            int n = tid >> 3, jj = tid & 7;            // 8 threads per node, 20 f32 each
            int cnt = cnt256[r * 32 + n];
            float inv = 1.0f / (float)(cnt > 0 ? cnt : 1);
            float* ap = agg + n * AGS + jj * 20;
            f32x4 q[5];
#pragma unroll
            for (int t = 0; t < 5; t++) q[t] = *reinterpret_cast<f32x4*>(ap + 4 * t);
#pragma unroll
            for (int t = 0; t < 5; t++) *reinterpret_cast<f32x4*>(ap + 4 * t) = (f32x4){0.f, 0.f, 0.f, 0.f};
            unsigned* fp = reinterpret_cast<unsigned*>(&feat[n * KP + jj * 20]);
#pragma unroll
            for (int t = 0; t < 5; t++) {
                unsigned lo = f2bf1(q[t][0] * inv) | (f2bf1(q[t][1] * inv) << 16);
                unsigned hi = f2bf1(q[t][2] * inv) | (f2bf1(q[t][3] * inv) << 16);
                fp[2 * t] = lo; fp[2 * t + 1] = hi;
            }
        }
        prev = r;
        __syncthreads();
    }
    mfma_pass(7);

    // ---- epilogue: bias + ReLU; C/D layout col=lane&15, row=(lane>>4)*4+i per 16x16 tile ----
    const int rq = lane >> 4;
#pragma unroll
    for (int ct = 0; ct < 2; ct++) {
        int col = wave * 32 + ct * 16 + (lane & 15);
        float bv = bias[col];
#pragma unroll
        for (int rt = 0; rt < 2; rt++) {
#pragma unroll
            for (int i = 0; i < 4; i++) {
                int n = n0 + rt * 16 + rq * 4 + i;
                float v = acc[rt * 2 + ct][i] + bv;
                out[(size_t)n * OC + col] = v > 0.f ? v : 0.f;
            }
        }
    }
}

extern "C" void kernel_launch(void* const* d_in, const int* in_sizes, int n_in,
                              void* d_out, int out_size, void* d_ws, size_t ws_size,
                              hipStream_t stream) {
    const float* x     = (const float*)d_in[0];
    const int*   ntype = (const int*)d_in[1];
    const int*   ei    = (const int*)d_in[2];
    const int*   et    = (const int*)d_in[3];
    const float* emb   = (const float*)d_in[4];
    const float* bases = (const float*)d_in[5];
    const float* comp  = (const float*)d_in[6];
    const float* rootw = (const float*)d_in[7];
    const float* bias  = (const float*)d_in[8];
    float* out = (float*)d_out;

    char* ws = (char*)d_ws;
    // 256-aligned layout, ~42 MB total:
    unsigned short* Wt     = (unsigned short*)(ws);              // 368,640
    unsigned short* h      = (unsigned short*)(ws + 368640);     // 32,000,000
    int*            ghist  = (int*)(ws + 32368640);              // 3,200,000 (256 x 3125)
    int*            total  = (int*)(ws + 35568640);              // 12,544
    int*            bstart = (int*)(ws + 35581184);              // 12,544
    unsigned*       slots  = (unsigned*)(ws + 35593728);         // 6,400,000

    k_prep   <<<NCH + 7813, 256, 0, stream>>>(x, ntype, emb, comp, bases, rootw, ei, h, Wt, ghist);
    k_total  <<<13,   256, 0, stream>>>(ghist, total);
    k_scanTot<<<1,    256, 0, stream>>>(total, bstart);
    k_offsets<<<13,   256, 0, stream>>>(ghist, bstart);
    k_scatter<<<NCH,  256, 0, stream>>>(ei, et, ghist, slots);
    k_mega   <<<NBKT, 256, 0, stream>>>(h, bias, Wt, bstart, slots, out);
}